// Round 1
// baseline (203.703 us; speedup 1.0000x reference)
//
#include <hip/hip_runtime.h>
#include <math.h>

#define BATCH 16
#define S_LEN 4096
#define D2c   256
#define D8c   1024
#define GNUM  24
#define QNUM  48
#define WINc  12

__device__ inline float4 f4max(float4 a, float4 b) {
    return make_float4(fmaxf(a.x, b.x), fmaxf(a.y, b.y), fmaxf(a.z, b.z), fmaxf(a.w, b.w));
}
__device__ inline float4 f4add(float4 a, float4 b) {
    return make_float4(a.x + b.x, a.y + b.y, a.z + b.z, a.w + b.w);
}

// ---------------------------------------------------------------------------
// Kernel P: full-sequence max/sum partials over S chunks for att and mod.
// Grid: [0, B*NC) -> att blocks; [B*NC, 2*B*NC) -> mod blocks. 256 threads.
// ---------------------------------------------------------------------------
__global__ __launch_bounds__(256) void pool_partials_kernel(
    const float* __restrict__ att, const float* __restrict__ mod,
    float* __restrict__ attPmax, float* __restrict__ attPsum,
    float* __restrict__ modPmax, float* __restrict__ modPsum,
    int NC, int CHUNK)
{
    const int tid = threadIdx.x;
    const int nAtt = BATCH * NC;
    const int bid = blockIdx.x;

    if (bid < nAtt) {
        // att: 256 threads x float4 = 1024 channels; loop CHUNK rows.
        const int b = bid / NC, ch = bid % NC;
        const float4* base = reinterpret_cast<const float4*>(att)
                             + (size_t)b * S_LEN * (D8c / 4) + tid;
        float4 mx = make_float4(-INFINITY, -INFINITY, -INFINITY, -INFINITY);
        float4 sm = make_float4(0.f, 0.f, 0.f, 0.f);
        const int r0 = ch * CHUNK;
        #pragma unroll 4
        for (int r = r0; r < r0 + CHUNK; ++r) {
            float4 v = base[(size_t)r * (D8c / 4)];
            mx = f4max(mx, v);
            sm = f4add(sm, v);
        }
        reinterpret_cast<float4*>(attPmax)[(size_t)bid * (D8c / 4) + tid] = mx;
        reinterpret_cast<float4*>(attPsum)[(size_t)bid * (D8c / 4) + tid] = sm;
    } else {
        // mod: 4 row-subgroups x 64 float4-channels.
        const int bid2 = bid - nAtt;
        const int b = bid2 / NC, ch = bid2 % NC;
        const int rg = tid >> 6, c4 = tid & 63;
        const float4* base = reinterpret_cast<const float4*>(mod)
                             + (size_t)b * S_LEN * (D2c / 4) + c4;
        float4 mx = make_float4(-INFINITY, -INFINITY, -INFINITY, -INFINITY);
        float4 sm = make_float4(0.f, 0.f, 0.f, 0.f);
        const int r0 = ch * CHUNK;
        #pragma unroll 4
        for (int r = r0 + rg; r < r0 + CHUNK; r += 4) {
            float4 v = base[(size_t)r * (D2c / 4)];
            mx = f4max(mx, v);
            sm = f4add(sm, v);
        }
        __shared__ float4 smx[256];
        __shared__ float4 ssm[256];
        smx[tid] = mx; ssm[tid] = sm;
        __syncthreads();
        if (rg == 0) {
            #pragma unroll
            for (int k = 1; k < 4; ++k) {
                mx = f4max(mx, smx[tid + (k << 6)]);
                sm = f4add(sm, ssm[tid + (k << 6)]);
            }
            reinterpret_cast<float4*>(modPmax)[(size_t)bid2 * (D2c / 4) + c4] = mx;
            reinterpret_cast<float4*>(modPsum)[(size_t)bid2 * (D2c / 4) + c4] = sm;
        }
    }
}

// ---------------------------------------------------------------------------
// Kernel B: bidaf att_2 logit contribution per (b,g), contracted against
// W_att2 (g>=1) / W_att_s2 (g==0). One block per batch, 256 threads.
// ---------------------------------------------------------------------------
__global__ __launch_bounds__(256) void bidaf_kernel(
    const float* __restrict__ mod, const float* __restrict__ q_enc,
    const int* __restrict__ gap_idx, const int* __restrict__ q_mask,
    const float* __restrict__ c_w, const float* __restrict__ q_w,
    const float* __restrict__ cq_w, const float* __restrict__ att_bias,
    const float* __restrict__ W_att2, const float* __restrict__ W_att_s2,
    float* __restrict__ att2_out /* [B*G] */)
{
    const int b = blockIdx.x;
    const int tid = threadIdx.x;

    __shared__ float c_sh[GNUM][D2c];     // gathered mod rows
    __shared__ float s_sh[GNUM][QNUM];
    __shared__ float sm1[GNUM][QNUM];
    __shared__ float sm2[GNUM][QNUM];
    __shared__ float v_sh[GNUM][QNUM];
    __shared__ float m_sh[GNUM][GNUM];
    __shared__ float s0[GNUM];
    __shared__ float s1[QNUM];
    __shared__ float u0[QNUM];            // dot(q_q, W_att_s2[256:512])
    __shared__ float u1[QNUM];            // dot(q_q, W_att2 [256:512])

    // Phase 1: gather c = mod_gaps
    for (int i = tid; i < GNUM * D2c; i += 256) {
        const int g = i / D2c, d = i % D2c;
        const int gid = gap_idx[b * GNUM + g];
        c_sh[g][d] = mod[((size_t)b * S_LEN + gid) * D2c + d];
    }
    __syncthreads();

    // Phase 2: s0, s1, u0, u1
    if (tid < GNUM) {
        float a = 0.f;
        for (int d = 0; d < D2c; ++d) a += c_sh[tid][d] * c_w[d];
        s0[tid] = a;
    } else if (tid >= 32 && tid < 32 + QNUM) {
        const int q = tid - 32;
        const float* qr = q_enc + ((size_t)b * QNUM + q) * D2c;
        float a = 0.f;
        for (int d = 0; d < D2c; ++d) a += qr[d] * q_w[d];
        s1[q] = a;
    } else if (tid >= 96 && tid < 96 + QNUM) {
        const int q = tid - 96;
        const float* qr = q_enc + ((size_t)b * QNUM + q) * D2c;
        float a = 0.f;
        for (int d = 0; d < D2c; ++d) a += qr[d] * W_att_s2[D2c + d];
        u0[q] = a;
    } else if (tid >= 160 && tid < 160 + QNUM) {
        const int q = tid - 160;
        const float* qr = q_enc + ((size_t)b * QNUM + q) * D2c;
        float a = 0.f;
        for (int d = 0; d < D2c; ++d) a += qr[d] * W_att2[D2c + d];
        u1[q] = a;
    }
    __syncthreads();

    // Phase 3: s matrix and v[g][q] = dot(c_g * wca_sel(g), q_q)
    const float bias = att_bias[0];
    for (int i = tid; i < GNUM * QNUM; i += 256) {
        const int g = i / QNUM, q = i % QNUM;
        const float* qr = q_enc + ((size_t)b * QNUM + q) * D2c;
        const float* wca = (g == 0) ? (W_att_s2 + 2 * D2c) : (W_att2 + 2 * D2c);
        float s2 = 0.f, vv = 0.f;
        for (int d = 0; d < D2c; ++d) {
            const float cq = c_sh[g][d] * qr[d];
            s2 += cq * cq_w[d];
            vv += cq * wca[d];
        }
        s_sh[g][q] = s0[g] + s1[q] + s2 + bias;
        v_sh[g][q] = vv;
    }
    __syncthreads();

    // Phase 4: softmaxes. sm1 over q (with q_mask), sm2 over g (c_mask all ones).
    if (tid < GNUM) {
        const int g = tid;
        float mxv = -1e30f;
        for (int q = 0; q < QNUM; ++q)
            if (q_mask[b * QNUM + q]) mxv = fmaxf(mxv, s_sh[g][q]);
        float sum = 0.f;
        for (int q = 0; q < QNUM; ++q) {
            const float e = q_mask[b * QNUM + q] ? __expf(s_sh[g][q] - mxv) : 0.f;
            sm1[g][q] = e;
            sum += e;
        }
        const float inv = 1.f / sum;
        for (int q = 0; q < QNUM; ++q) sm1[g][q] *= inv;
    } else if (tid >= 64 && tid < 64 + QNUM) {
        const int q = tid - 64;
        float mxv = -1e30f;
        for (int g = 0; g < GNUM; ++g) mxv = fmaxf(mxv, s_sh[g][q]);
        float sum = 0.f;
        for (int g = 0; g < GNUM; ++g) {
            const float e = __expf(s_sh[g][q] - mxv);
            sm2[g][q] = e;
            sum += e;
        }
        const float inv = 1.f / sum;
        for (int g = 0; g < GNUM; ++g) sm2[g][q] *= inv;
    }
    __syncthreads();

    // Phase 5: m[g][k] = sum_d c_g[d]*c_k[d]*wcb_sel(g)[d]
    for (int i = tid; i < GNUM * GNUM; i += 256) {
        const int g = i / GNUM, k = i % GNUM;
        const float* wcb = (g == 0) ? (W_att_s2 + 3 * D2c) : (W_att2 + 3 * D2c);
        float a = 0.f;
        for (int d = 0; d < D2c; ++d) a += c_sh[g][d] * c_sh[k][d] * wcb[d];
        m_sh[g][k] = a;
    }
    __syncthreads();

    // Phase 6: att2 logit per g
    if (tid < GNUM) {
        const int g = tid;
        const float* wc = (g == 0) ? W_att_s2 : W_att2;
        const float* uu = (g == 0) ? u0 : u1;
        float acc = 0.f;
        for (int d = 0; d < D2c; ++d) acc += c_sh[g][d] * wc[d];
        for (int q = 0; q < QNUM; ++q) acc += sm1[g][q] * (uu[q] + v_sh[g][q]);
        for (int k = 0; k < GNUM; ++k) {
            float ss = 0.f;
            for (int q = 0; q < QNUM; ++q) ss += sm1[g][q] * sm2[k][q];
            acc += ss * m_sh[g][k];
        }
        att2_out[b * GNUM + g] = acc;
    }
}

// ---------------------------------------------------------------------------
// Kernel F: per-(b,g) windowed pools (g>=1) or partial-combine (g==0),
// gather dots, final logit. One block per (b,g), 256 threads.
// ---------------------------------------------------------------------------
__global__ __launch_bounds__(256) void final_kernel(
    const float* __restrict__ att, const float* __restrict__ mod,
    const int* __restrict__ gap_idx, const int* __restrict__ mask,
    const float* __restrict__ W_att,  const float* __restrict__ b_att,
    const float* __restrict__ W_mod,  const float* __restrict__ b_mod,
    const float* __restrict__ b_att2,
    const float* __restrict__ W_att_s, const float* __restrict__ b_att_s,
    const float* __restrict__ W_mod_s, const float* __restrict__ b_mod_s,
    const float* __restrict__ b_att_s2,
    const float* __restrict__ attPmax, const float* __restrict__ attPsum,
    const float* __restrict__ modPmax, const float* __restrict__ modPsum,
    const float* __restrict__ att2_ws,
    float* __restrict__ out, int NC)
{
    const int bg = blockIdx.x;
    const int b = bg / GNUM, g = bg % GNUM;
    const int tid = threadIdx.x;
    const int gid = gap_idx[bg];

    const float* Wa = g ? W_att : W_att_s;   // [3*D8]
    const float* Wm = g ? W_mod : W_mod_s;   // [3*D2]

    __shared__ float redA[256];
    __shared__ float redB[256];

    float acc = 0.f;

    // gather dots
    const float* arow = att + ((size_t)b * S_LEN + gid) * D8c;
    for (int d = tid; d < D8c; d += 256) acc += arow[d] * Wa[d];
    const float* mrow = mod + ((size_t)b * S_LEN + gid) * D2c;
    if (tid < D2c) acc += mrow[tid] * Wm[tid];

    if (g == 0) {
        // denom0 = sum(mask[b,:])
        float cnt = 0.f;
        for (int s = tid; s < S_LEN; s += 256) cnt += (mask[b * S_LEN + s] != 0) ? 1.f : 0.f;
        redA[tid] = cnt;
        __syncthreads();
        for (int off = 128; off > 0; off >>= 1) {
            if (tid < off) redA[tid] += redA[tid + off];
            __syncthreads();
        }
        const float rden0 = 1.f / redA[0];

        // combine full-seq partials
        for (int d = tid; d < D8c; d += 256) {
            float mx = -INFINITY, sm = 0.f;
            for (int ch = 0; ch < NC; ++ch) {
                const size_t idx = ((size_t)(b * NC + ch)) * D8c + d;
                mx = fmaxf(mx, attPmax[idx]);
                sm += attPsum[idx];
            }
            acc += mx * Wa[D8c + d] + (sm * rden0) * Wa[2 * D8c + d];
        }
        if (tid < D2c) {
            float mx = -INFINITY, sm = 0.f;
            for (int ch = 0; ch < NC; ++ch) {
                const size_t idx = ((size_t)(b * NC + ch)) * D2c + tid;
                mx = fmaxf(mx, modPmax[idx]);
                sm += modPsum[idx];
            }
            acc += mx * Wm[D2c + tid] + (sm * rden0) * Wm[2 * D2c + tid];
        }
    } else {
        const int lo = (gid - WINc > 0) ? gid - WINc : 0;
        const int hi = (gid + WINc < S_LEN - 1) ? gid + WINc : S_LEN - 1;
        float den = 0.f;
        for (int s = lo; s <= hi; ++s) den += (mask[b * S_LEN + s] != 0) ? 1.f : 0.f;
        const float rden = 1.f / den;

        for (int d = tid; d < D8c; d += 256) {
            float mx = 0.f, sm = 0.f;   // max clamped at 0: zeros outside window dominate
            for (int s = lo; s <= hi; ++s) {
                if (mask[b * S_LEN + s]) {
                    const float v = att[((size_t)b * S_LEN + s) * D8c + d];
                    mx = fmaxf(mx, v);
                    sm += v;
                }
            }
            acc += mx * Wa[D8c + d] + (sm * rden) * Wa[2 * D8c + d];
        }
        if (tid < D2c) {
            float mx = 0.f, sm = 0.f;
            for (int s = lo; s <= hi; ++s) {
                if (mask[b * S_LEN + s]) {
                    const float v = mod[((size_t)b * S_LEN + s) * D2c + tid];
                    mx = fmaxf(mx, v);
                    sm += v;
                }
            }
            acc += mx * Wm[D2c + tid] + (sm * rden) * Wm[2 * D2c + tid];
        }
    }

    // block reduce acc
    redB[tid] = acc;
    __syncthreads();
    for (int off = 128; off > 0; off >>= 1) {
        if (tid < off) redB[tid] += redB[tid + off];
        __syncthreads();
    }
    if (tid == 0) {
        const float biases = g ? (b_att[0] + b_mod[0] + b_att2[0])
                               : (b_att_s[0] + b_mod_s[0] + b_att_s2[0]);
        out[bg] = redB[0] + att2_ws[bg] + biases;
    }
}

// ---------------------------------------------------------------------------
extern "C" void kernel_launch(void* const* d_in, const int* in_sizes, int n_in,
                              void* d_out, int out_size, void* d_ws, size_t ws_size,
                              hipStream_t stream)
{
    const float* att      = (const float*)d_in[0];
    const float* mod      = (const float*)d_in[1];
    const float* q_enc    = (const float*)d_in[2];
    const int*   gap_idx  = (const int*)  d_in[3];
    const int*   mask     = (const int*)  d_in[4];
    const int*   q_mask   = (const int*)  d_in[5];
    const float* c_w      = (const float*)d_in[6];
    const float* q_w      = (const float*)d_in[7];
    const float* cq_w     = (const float*)d_in[8];
    const float* att_bias = (const float*)d_in[9];
    const float* W_att    = (const float*)d_in[10];
    const float* b_att    = (const float*)d_in[11];
    const float* W_mod    = (const float*)d_in[12];
    const float* b_mod    = (const float*)d_in[13];
    const float* W_att2   = (const float*)d_in[14];
    const float* b_att2   = (const float*)d_in[15];
    const float* W_att_s  = (const float*)d_in[16];
    const float* b_att_s  = (const float*)d_in[17];
    const float* W_mod_s  = (const float*)d_in[18];
    const float* b_mod_s  = (const float*)d_in[19];
    const float* W_att_s2 = (const float*)d_in[20];
    const float* b_att_s2 = (const float*)d_in[21];

    float* out = (float*)d_out;

    // choose NC (S chunks) to fit workspace
    int NC = 32;
    for (;;) {
        size_t need = ((size_t)BATCH * NC * D8c * 2 + (size_t)BATCH * NC * D2c * 2
                       + (size_t)BATCH * GNUM) * sizeof(float);
        if (need <= ws_size || NC == 1) break;
        NC >>= 1;
    }
    const int CHUNK = S_LEN / NC;

    float* ws = (float*)d_ws;
    float* attPmax = ws;
    float* attPsum = attPmax + (size_t)BATCH * NC * D8c;
    float* modPmax = attPsum + (size_t)BATCH * NC * D8c;
    float* modPsum = modPmax + (size_t)BATCH * NC * D2c;
    float* att2ws  = modPsum + (size_t)BATCH * NC * D2c;

    pool_partials_kernel<<<BATCH * NC * 2, 256, 0, stream>>>(
        att, mod, attPmax, attPsum, modPmax, modPsum, NC, CHUNK);

    bidaf_kernel<<<BATCH, 256, 0, stream>>>(
        mod, q_enc, gap_idx, q_mask, c_w, q_w, cq_w, att_bias,
        W_att2, W_att_s2, att2ws);

    final_kernel<<<BATCH * GNUM, 256, 0, stream>>>(
        att, mod, gap_idx, mask,
        W_att, b_att, W_mod, b_mod, b_att2,
        W_att_s, b_att_s, W_mod_s, b_mod_s, b_att_s2,
        attPmax, attPsum, modPmax, modPsum, att2ws,
        out, NC);
}

// Round 2
// 154.265 us; speedup vs baseline: 1.3205x; 1.3205x over previous
//
#include <hip/hip_runtime.h>
#include <math.h>

#define BATCH 16
#define S_LEN 4096
#define D2c   256
#define D8c   1024
#define GNUM  24
#define QNUM  48
#define WINc  12
#define NCA   64    // att chunks per batch (64 rows each)
#define NCM   16    // mod blocks per batch (256 rows each, 4 sub-slots of 64)
#define NSLOT 64    // partial slots per batch (att: NCA, mod: NCM*4)

__device__ inline float4 f4max(float4 a, float4 b) {
    return make_float4(fmaxf(a.x,b.x), fmaxf(a.y,b.y), fmaxf(a.z,b.z), fmaxf(a.w,b.w));
}
__device__ inline float4 f4add(float4 a, float4 b) {
    return make_float4(a.x+b.x, a.y+b.y, a.z+b.z, a.w+b.w);
}
__device__ inline float dot4(float4 a, float4 b) {
    return a.x*b.x + a.y*b.y + a.z*b.z + a.w*b.w;
}

struct BidafSh {
    float c[GNUM][D2c];
    float s[GNUM][QNUM];
    float sm1[GNUM][QNUM];
    float sm2[GNUM][QNUM];
    float v[GNUM][QNUM];
    float m[GNUM][GNUM];
    float s0[GNUM];
    float s1[QNUM];
    float u0[QNUM];
    float u1[QNUM];
};
struct WinSh {
    float wmf[32];
    float rden;
    float red[256];
};
union ShU { BidafSh bi; WinSh w; };

// ---------------------------------------------------------------------------
// K1: fused bidaf (16 blocks) + att partials (1024) + mod partials (256) +
//     per-(b,g>=1) window pooling & partial logit (368). One launch so the
//     serial/latency-bound blocks hide under the BW-bound streaming blocks.
// ---------------------------------------------------------------------------
__global__ __launch_bounds__(256) void k1_kernel(
    const float* __restrict__ att, const float* __restrict__ mod,
    const float* __restrict__ q_enc,
    const int* __restrict__ gap_idx, const int* __restrict__ mask,
    const int* __restrict__ q_mask,
    const float* __restrict__ c_w, const float* __restrict__ q_w,
    const float* __restrict__ cq_w, const float* __restrict__ att_bias,
    const float* __restrict__ W_att2, const float* __restrict__ W_att_s2,
    const float* __restrict__ W_att, const float* __restrict__ W_mod,
    float* __restrict__ attPmax, float* __restrict__ attPsum,
    float* __restrict__ modPmax, float* __restrict__ modPsum,
    float* __restrict__ att2ws, float* __restrict__ winpart)
{
    __shared__ ShU sh;
    const int tid = threadIdx.x;
    const int bid = blockIdx.x;

    if (bid < BATCH) {
        // ------------------------------ bidaf, b = bid -------------------
        const int b = bid;

        // Phase 1: gather c = mod_gaps (float4)
        for (int i = tid; i < GNUM * (D2c/4); i += 256) {
            const int g = i / (D2c/4), d4 = i % (D2c/4);
            const int gid = gap_idx[b * GNUM + g];
            reinterpret_cast<float4*>(sh.bi.c[g])[d4] =
                reinterpret_cast<const float4*>(mod)[((size_t)b * S_LEN + gid) * (D2c/4) + d4];
        }
        __syncthreads();

        // Phase 2: s0, s1, u0, u1
        if (tid < GNUM) {
            const float4* cr = reinterpret_cast<const float4*>(sh.bi.c[tid]);
            const float4* w4 = reinterpret_cast<const float4*>(c_w);
            float a = 0.f;
            for (int d = 0; d < D2c/4; ++d) a += dot4(cr[d], w4[d]);
            sh.bi.s0[tid] = a;
        } else if (tid >= 32 && tid < 32 + QNUM) {
            const int q = tid - 32;
            const float4* qr = reinterpret_cast<const float4*>(q_enc + ((size_t)b*QNUM + q)*D2c);
            const float4* w4 = reinterpret_cast<const float4*>(q_w);
            float a = 0.f;
            for (int d = 0; d < D2c/4; ++d) a += dot4(qr[d], w4[d]);
            sh.bi.s1[q] = a;
        } else if (tid >= 96 && tid < 96 + QNUM) {
            const int q = tid - 96;
            const float4* qr = reinterpret_cast<const float4*>(q_enc + ((size_t)b*QNUM + q)*D2c);
            const float4* w4 = reinterpret_cast<const float4*>(W_att_s2 + D2c);
            float a = 0.f;
            for (int d = 0; d < D2c/4; ++d) a += dot4(qr[d], w4[d]);
            sh.bi.u0[q] = a;
        } else if (tid >= 160 && tid < 160 + QNUM) {
            const int q = tid - 160;
            const float4* qr = reinterpret_cast<const float4*>(q_enc + ((size_t)b*QNUM + q)*D2c);
            const float4* w4 = reinterpret_cast<const float4*>(W_att2 + D2c);
            float a = 0.f;
            for (int d = 0; d < D2c/4; ++d) a += dot4(qr[d], w4[d]);
            sh.bi.u1[q] = a;
        }
        __syncthreads();

        // Phase 3: s matrix + v[g][q] = dot(c_g * wca_sel(g), q_q)
        const float bias = att_bias[0];
        for (int i = tid; i < GNUM * QNUM; i += 256) {
            const int g = i / QNUM, q = i % QNUM;
            const float4* qr  = reinterpret_cast<const float4*>(q_enc + ((size_t)b*QNUM + q)*D2c);
            const float4* cw  = reinterpret_cast<const float4*>(cq_w);
            const float4* wca = reinterpret_cast<const float4*>(((g == 0) ? W_att_s2 : W_att2) + 2*D2c);
            const float4* cr  = reinterpret_cast<const float4*>(sh.bi.c[g]);
            float s2 = 0.f, vv = 0.f;
            for (int d = 0; d < D2c/4; ++d) {
                const float4 cc = cr[d], qq = qr[d];
                const float4 cq = make_float4(cc.x*qq.x, cc.y*qq.y, cc.z*qq.z, cc.w*qq.w);
                s2 += dot4(cq, cw[d]);
                vv += dot4(cq, wca[d]);
            }
            sh.bi.s[g][q] = sh.bi.s0[g] + sh.bi.s1[q] + s2 + bias;
            sh.bi.v[g][q] = vv;
        }
        __syncthreads();

        // Phase 4: softmaxes
        if (tid < GNUM) {
            const int g = tid;
            float mxv = -1e30f;
            for (int q = 0; q < QNUM; ++q)
                if (q_mask[b*QNUM + q]) mxv = fmaxf(mxv, sh.bi.s[g][q]);
            float sum = 0.f;
            for (int q = 0; q < QNUM; ++q) {
                const float e = q_mask[b*QNUM + q] ? __expf(sh.bi.s[g][q] - mxv) : 0.f;
                sh.bi.sm1[g][q] = e;
                sum += e;
            }
            const float inv = 1.f / sum;
            for (int q = 0; q < QNUM; ++q) sh.bi.sm1[g][q] *= inv;
        } else if (tid >= 64 && tid < 64 + QNUM) {
            const int q = tid - 64;
            float mxv = -1e30f;
            for (int g = 0; g < GNUM; ++g) mxv = fmaxf(mxv, sh.bi.s[g][q]);
            float sum = 0.f;
            for (int g = 0; g < GNUM; ++g) {
                const float e = __expf(sh.bi.s[g][q] - mxv);
                sh.bi.sm2[g][q] = e;
                sum += e;
            }
            const float inv = 1.f / sum;
            for (int g = 0; g < GNUM; ++g) sh.bi.sm2[g][q] *= inv;
        }
        __syncthreads();

        // Phase 5: m[g][k] = sum_d c_g[d]*c_k[d]*wcb_sel(g)[d]
        for (int i = tid; i < GNUM * GNUM; i += 256) {
            const int g = i / GNUM, k = i % GNUM;
            const float4* wcb = reinterpret_cast<const float4*>(((g == 0) ? W_att_s2 : W_att2) + 3*D2c);
            const float4* cg = reinterpret_cast<const float4*>(sh.bi.c[g]);
            const float4* ck = reinterpret_cast<const float4*>(sh.bi.c[k]);
            float a = 0.f;
            for (int d = 0; d < D2c/4; ++d) {
                const float4 x = cg[d], y = ck[d], w = wcb[d];
                a += x.x*y.x*w.x + x.y*y.y*w.y + x.z*y.z*w.z + x.w*y.w*w.w;
            }
            sh.bi.m[g][k] = a;
        }
        __syncthreads();

        // Phase 6: att2 logit per g
        if (tid < GNUM) {
            const int g = tid;
            const float* wc = (g == 0) ? W_att_s2 : W_att2;
            const float* uu = (g == 0) ? sh.bi.u0 : sh.bi.u1;
            float acc = 0.f;
            for (int d = 0; d < D2c; ++d) acc += sh.bi.c[g][d] * wc[d];
            for (int q = 0; q < QNUM; ++q) acc += sh.bi.sm1[g][q] * (uu[q] + sh.bi.v[g][q]);
            for (int k = 0; k < GNUM; ++k) {
                float ss = 0.f;
                for (int q = 0; q < QNUM; ++q) ss += sh.bi.sm1[g][q] * sh.bi.sm2[k][q];
                acc += ss * sh.bi.m[g][k];
            }
            att2ws[b * GNUM + g] = acc;
        }
    } else if (bid < BATCH + BATCH*NCA) {
        // ------------------------------ att partials ---------------------
        const int ab = bid - BATCH;
        const int b = ab >> 6, ch = ab & 63;
        const float4* base = reinterpret_cast<const float4*>(att)
                             + ((size_t)b * S_LEN + ch * 64) * (D8c/4) + tid;
        float4 mx = make_float4(-INFINITY, -INFINITY, -INFINITY, -INFINITY);
        float4 sm = make_float4(0.f, 0.f, 0.f, 0.f);
        #pragma unroll 8
        for (int r = 0; r < 64; ++r) {
            const float4 v = base[(size_t)r * (D8c/4)];
            mx = f4max(mx, v);
            sm = f4add(sm, v);
        }
        reinterpret_cast<float4*>(attPmax)[(size_t)ab * (D8c/4) + tid] = mx;
        reinterpret_cast<float4*>(attPsum)[(size_t)ab * (D8c/4) + tid] = sm;
    } else if (bid < BATCH + BATCH*NCA + BATCH*NCM) {
        // ------------------------------ mod partials ---------------------
        const int mb = bid - BATCH - BATCH*NCA;
        const int b = mb >> 4, ch = mb & 15;
        const int rg = tid >> 6, c4 = tid & 63;
        const float4* base = reinterpret_cast<const float4*>(mod)
                             + ((size_t)b * S_LEN + ch * 256 + rg * 64) * (D2c/4) + c4;
        float4 mx = make_float4(-INFINITY, -INFINITY, -INFINITY, -INFINITY);
        float4 sm = make_float4(0.f, 0.f, 0.f, 0.f);
        #pragma unroll 8
        for (int r = 0; r < 64; ++r) {
            const float4 v = base[(size_t)r * (D2c/4)];
            mx = f4max(mx, v);
            sm = f4add(sm, v);
        }
        const int slot = (b * NCM + ch) * 4 + rg;   // = b*64 + ch*4 + rg
        reinterpret_cast<float4*>(modPmax)[(size_t)slot * (D2c/4) + c4] = mx;
        reinterpret_cast<float4*>(modPsum)[(size_t)slot * (D2c/4) + c4] = sm;
    } else {
        // ------------------------------ window blocks (g>=1) -------------
        const int wb = bid - BATCH - BATCH*NCA - BATCH*NCM;
        const int b = wb / (GNUM - 1), g = wb % (GNUM - 1) + 1;
        const int gid = gap_idx[b * GNUM + g];
        const int lo = (gid - WINc > 0) ? gid - WINc : 0;
        const int hi = (gid + WINc < S_LEN - 1) ? gid + WINc : S_LEN - 1;
        const int n = hi - lo + 1;

        if (tid < n) sh.w.wmf[tid] = (mask[b * S_LEN + lo + tid] != 0) ? 1.f : 0.f;
        __syncthreads();
        if (tid == 0) {
            float d = 0.f;
            for (int i = 0; i < n; ++i) d += sh.w.wmf[i];
            sh.w.rden = 1.f / d;
        }
        __syncthreads();
        const float rden = sh.w.rden;

        const float4* Wa4 = reinterpret_cast<const float4*>(W_att);
        const float4* Wm4 = reinterpret_cast<const float4*>(W_mod);

        float acc = 0.f;
        {
            const float4* base = reinterpret_cast<const float4*>(att)
                                 + ((size_t)b * S_LEN + lo) * (D8c/4) + tid;
            float4 mx = make_float4(0.f, 0.f, 0.f, 0.f);  // max clamped at 0 (zeros outside window)
            float4 sm = make_float4(0.f, 0.f, 0.f, 0.f);
            for (int i = 0; i < n; ++i) {
                if (sh.w.wmf[i] != 0.f) {
                    const float4 v = base[(size_t)i * (D8c/4)];
                    mx = f4max(mx, v);
                    sm = f4add(sm, v);
                }
            }
            acc += dot4(mx, Wa4[(D8c/4) + tid]) + dot4(sm, Wa4[2*(D8c/4) + tid]) * rden;
            const float4 ar = reinterpret_cast<const float4*>(att)[((size_t)b * S_LEN + gid) * (D8c/4) + tid];
            acc += dot4(ar, Wa4[tid]);
        }
        if (tid < D2c/4) {
            const float4* base = reinterpret_cast<const float4*>(mod)
                                 + ((size_t)b * S_LEN + lo) * (D2c/4) + tid;
            float4 mx = make_float4(0.f, 0.f, 0.f, 0.f);
            float4 sm = make_float4(0.f, 0.f, 0.f, 0.f);
            for (int i = 0; i < n; ++i) {
                if (sh.w.wmf[i] != 0.f) {
                    const float4 v = base[(size_t)i * (D2c/4)];
                    mx = f4max(mx, v);
                    sm = f4add(sm, v);
                }
            }
            acc += dot4(mx, Wm4[(D2c/4) + tid]) + dot4(sm, Wm4[2*(D2c/4) + tid]) * rden;
            const float4 mr = reinterpret_cast<const float4*>(mod)[((size_t)b * S_LEN + gid) * (D2c/4) + tid];
            acc += dot4(mr, Wm4[tid]);
        }

        sh.w.red[tid] = acc;
        __syncthreads();
        for (int off = 128; off > 0; off >>= 1) {
            if (tid < off) sh.w.red[tid] += sh.w.red[tid + off];
            __syncthreads();
        }
        if (tid == 0) winpart[b * GNUM + g] = sh.w.red[0];
    }
}

// ---------------------------------------------------------------------------
// K2: per-batch g==0 combine + final output assembly. 16 blocks.
// ---------------------------------------------------------------------------
__global__ __launch_bounds__(256) void k2_kernel(
    const float* __restrict__ att, const float* __restrict__ mod,
    const int* __restrict__ gap_idx, const int* __restrict__ mask,
    const float* __restrict__ W_att_s, const float* __restrict__ W_mod_s,
    const float* __restrict__ b_att, const float* __restrict__ b_mod,
    const float* __restrict__ b_att2,
    const float* __restrict__ b_att_s, const float* __restrict__ b_mod_s,
    const float* __restrict__ b_att_s2,
    const float* __restrict__ attPmax, const float* __restrict__ attPsum,
    const float* __restrict__ modPmax, const float* __restrict__ modPsum,
    const float* __restrict__ att2ws, const float* __restrict__ winpart,
    float* __restrict__ out)
{
    const int b = blockIdx.x;
    const int tid = threadIdx.x;
    __shared__ float red[256];
    __shared__ float rdensh;

    // denom0 = sum(mask[b,:])
    float cnt = 0.f;
    for (int s = tid; s < S_LEN; s += 256) cnt += (mask[b * S_LEN + s] != 0) ? 1.f : 0.f;
    red[tid] = cnt;
    __syncthreads();
    for (int off = 128; off > 0; off >>= 1) {
        if (tid < off) red[tid] += red[tid + off];
        __syncthreads();
    }
    if (tid == 0) rdensh = 1.f / red[0];
    __syncthreads();
    const float rden0 = rdensh;

    const int gid0 = gap_idx[b * GNUM];
    const float4* Wa4 = reinterpret_cast<const float4*>(W_att_s);
    const float4* Wm4 = reinterpret_cast<const float4*>(W_mod_s);

    float acc = 0.f;
    {
        float4 mx = make_float4(-INFINITY, -INFINITY, -INFINITY, -INFINITY);
        float4 sm = make_float4(0.f, 0.f, 0.f, 0.f);
        #pragma unroll 8
        for (int ch = 0; ch < NSLOT; ++ch) {
            const size_t idx = ((size_t)b * NSLOT + ch) * (D8c/4) + tid;
            mx = f4max(mx, reinterpret_cast<const float4*>(attPmax)[idx]);
            sm = f4add(sm, reinterpret_cast<const float4*>(attPsum)[idx]);
        }
        acc += dot4(mx, Wa4[(D8c/4) + tid]) + dot4(sm, Wa4[2*(D8c/4) + tid]) * rden0;
        const float4 ar = reinterpret_cast<const float4*>(att)[((size_t)b * S_LEN + gid0) * (D8c/4) + tid];
        acc += dot4(ar, Wa4[tid]);
    }
    if (tid < D2c/4) {
        float4 mx = make_float4(-INFINITY, -INFINITY, -INFINITY, -INFINITY);
        float4 sm = make_float4(0.f, 0.f, 0.f, 0.f);
        #pragma unroll 8
        for (int ch = 0; ch < NSLOT; ++ch) {
            const size_t idx = ((size_t)b * NSLOT + ch) * (D2c/4) + tid;
            mx = f4max(mx, reinterpret_cast<const float4*>(modPmax)[idx]);
            sm = f4add(sm, reinterpret_cast<const float4*>(modPsum)[idx]);
        }
        acc += dot4(mx, Wm4[(D2c/4) + tid]) + dot4(sm, Wm4[2*(D2c/4) + tid]) * rden0;
        const float4 mr = reinterpret_cast<const float4*>(mod)[((size_t)b * S_LEN + gid0) * (D2c/4) + tid];
        acc += dot4(mr, Wm4[tid]);
    }

    __syncthreads();
    red[tid] = acc;
    __syncthreads();
    for (int off = 128; off > 0; off >>= 1) {
        if (tid < off) red[tid] += red[tid + off];
        __syncthreads();
    }
    if (tid == 0) {
        out[b * GNUM] = red[0] + att2ws[b * GNUM] + b_att_s[0] + b_mod_s[0] + b_att_s2[0];
    } else if (tid < GNUM) {
        out[b * GNUM + tid] = winpart[b * GNUM + tid] + att2ws[b * GNUM + tid]
                              + b_att[0] + b_mod[0] + b_att2[0];
    }
}

// ---------------------------------------------------------------------------
extern "C" void kernel_launch(void* const* d_in, const int* in_sizes, int n_in,
                              void* d_out, int out_size, void* d_ws, size_t ws_size,
                              hipStream_t stream)
{
    const float* att      = (const float*)d_in[0];
    const float* mod      = (const float*)d_in[1];
    const float* q_enc    = (const float*)d_in[2];
    const int*   gap_idx  = (const int*)  d_in[3];
    const int*   mask     = (const int*)  d_in[4];
    const int*   q_mask   = (const int*)  d_in[5];
    const float* c_w      = (const float*)d_in[6];
    const float* q_w      = (const float*)d_in[7];
    const float* cq_w     = (const float*)d_in[8];
    const float* att_bias = (const float*)d_in[9];
    const float* W_att    = (const float*)d_in[10];
    const float* b_att    = (const float*)d_in[11];
    const float* W_mod    = (const float*)d_in[12];
    const float* b_mod    = (const float*)d_in[13];
    const float* W_att2   = (const float*)d_in[14];
    const float* b_att2   = (const float*)d_in[15];
    const float* W_att_s  = (const float*)d_in[16];
    const float* b_att_s  = (const float*)d_in[17];
    const float* W_mod_s  = (const float*)d_in[18];
    const float* b_mod_s  = (const float*)d_in[19];
    const float* W_att_s2 = (const float*)d_in[20];
    const float* b_att_s2 = (const float*)d_in[21];

    float* out = (float*)d_out;

    float* ws = (float*)d_ws;
    float* attPmax = ws;                                            // 16*64*1024
    float* attPsum = attPmax + (size_t)BATCH * NSLOT * D8c;
    float* modPmax = attPsum + (size_t)BATCH * NSLOT * D8c;         // 16*64*256
    float* modPsum = modPmax + (size_t)BATCH * NSLOT * D2c;
    float* att2ws  = modPsum + (size_t)BATCH * NSLOT * D2c;         // 384
    float* winpart = att2ws  + (size_t)BATCH * GNUM;                // 384

    const int grid1 = BATCH + BATCH*NCA + BATCH*NCM + BATCH*(GNUM-1);

    k1_kernel<<<grid1, 256, 0, stream>>>(
        att, mod, q_enc, gap_idx, mask, q_mask,
        c_w, q_w, cq_w, att_bias, W_att2, W_att_s2, W_att, W_mod,
        attPmax, attPsum, modPmax, modPsum, att2ws, winpart);

    k2_kernel<<<BATCH, 256, 0, stream>>>(
        att, mod, gap_idx, mask, W_att_s, W_mod_s,
        b_att, b_mod, b_att2, b_att_s, b_mod_s, b_att_s2,
        attPmax, attPsum, modPmax, modPsum, att2ws, winpart, out);
}